// Round 7
// baseline (134.421 us; speedup 1.0000x reference)
//
#include <hip/hip_runtime.h>
#include <math.h>

#define IN_F 128
#define OUT_F 64
#define ALPHA 0.2f
#define INV_SQRT_F 0.125f   // 1/sqrt(OUT_F)
#define CAP 64              // per-src bucket capacity; P(deg>64) ~ 1e-20
#define SUBSH 6             // 64 srcs per sub-bin (partition granularity = gather granularity)
#define SUBSZ 64
#define CAPH 2048           // per-sub-bin edge capacity (mean 1024, +32 sigma)
#define HS 136              // f16 LDS row stride: b128 frag reads 2-way = free

typedef _Float16 h8  __attribute__((ext_vector_type(8)));
typedef float    f4  __attribute__((ext_vector_type(4)));
typedef int      i4  __attribute__((ext_vector_type(4)));   // clang vector: nontemporal-ok

__device__ __forceinline__ float edge_w(float sc) {
    float lr = sc > 0.f ? sc : ALPHA * sc;
    return __expf(lr * INV_SQRT_F);
}

__device__ __forceinline__ h8 cvt8(float4 a, float4 b) {
    h8 r;
    r[0] = (_Float16)a.x; r[1] = (_Float16)a.y;
    r[2] = (_Float16)a.z; r[3] = (_Float16)a.w;
    r[4] = (_Float16)b.x; r[5] = (_Float16)b.y;
    r[6] = (_Float16)b.z; r[7] = (_Float16)b.w;
    return r;
}

// ---------------------------------------------------------------------------
// Pass 1 (block-specialized):
//   blocks [0, g_p1): edge partition by src>>6 (64-src sub-bins, 1:1 with
//     k_bin blocks). LDS histogram -> one device atomic per touched sub-bin
//     -> packed (srclow<<16|dst) chunks. src/dst/pk accesses nontemporal
//     (streaming; keep L2 for h/data_h).
//   blocks [g_p1, ...): MFMA f16 GEMM, 64 nodes/block, A-tile + epilogue
//     vectors prefetched before the W-stage barrier.
// ---------------------------------------------------------------------------
__global__ __launch_bounds__(256, 4) void k_p1(
    const float* __restrict__ h, const float* __restrict__ W,
    const float* __restrict__ b, const float* __restrict__ a,
    const int* __restrict__ src, const int* __restrict__ dst,
    int* __restrict__ gcur, unsigned* __restrict__ pk,
    _Float16* __restrict__ data_h,
    float* __restrict__ s_src, float* __restrict__ s_dst,
    int n_nodes, int n_edges, int g_p1)
{
    __shared__ _Float16 wsh[OUT_F * HS];   // 17408 B
    __shared__ int hist[1024];
    __shared__ int off[1024];
    const int tid = threadIdx.x;

    if ((int)blockIdx.x < g_p1) {
        // ---- partition part ----
        const int nsub = (n_nodes + SUBSZ - 1) >> SUBSH;
        const int e0 = (int)blockIdx.x * 4096 + tid * 16;

        for (int i = tid; i < nsub; i += 256) hist[i] = 0;
        __syncthreads();

        int s[16], d[16];
        const bool full = (e0 + 16 <= n_edges);
        if (full) {
            #pragma unroll
            for (int c = 0; c < 4; ++c) {
                i4 s4 = __builtin_nontemporal_load((const i4*)&src[e0 + c * 4]);
                i4 d4 = __builtin_nontemporal_load((const i4*)&dst[e0 + c * 4]);
                s[c*4+0] = s4[0]; s[c*4+1] = s4[1]; s[c*4+2] = s4[2]; s[c*4+3] = s4[3];
                d[c*4+0] = d4[0]; d[c*4+1] = d4[1]; d[c*4+2] = d4[2]; d[c*4+3] = d4[3];
            }
            #pragma unroll
            for (int i = 0; i < 16; ++i)
                atomicAdd(&hist[s[i] >> SUBSH], 1);
        } else {
            #pragma unroll
            for (int i = 0; i < 16; ++i) {
                int e = e0 + i;
                s[i] = (e < n_edges) ? src[e] : -1;
                d[i] = (e < n_edges) ? dst[e] : 0;
                if (s[i] >= 0) atomicAdd(&hist[s[i] >> SUBSH], 1);
            }
        }
        __syncthreads();

        for (int i = tid; i < nsub; i += 256) {
            int c = hist[i];
            off[i] = (c > 0) ? atomicAdd(&gcur[i], c) : 0;
            hist[i] = 0;
        }
        __syncthreads();

        #pragma unroll
        for (int i = 0; i < 16; ++i) {
            if (s[i] < 0) continue;
            int sub = s[i] >> SUBSH;
            int r = atomicAdd(&hist[sub], 1);
            int p = off[sub] + r;
            if (p < CAPH)
                __builtin_nontemporal_store(
                    ((unsigned)(s[i] & (SUBSZ - 1)) << 16) | (unsigned)d[i],
                    &pk[(size_t)sub * CAPH + p]);
        }
        return;
    }

    // ---- GEMM part: 64 nodes per block, A prefetched before W stage ----
    const int node0 = ((int)blockIdx.x - g_p1) * 64;

    const int wv  = tid >> 6;
    const int lane = tid & 63;
    const int q   = lane >> 4;     // quad
    const int col = lane & 15;
    const int r0  = wv * 16;

    const int arow = min(node0 + r0 + col, n_nodes - 1);   // A row (node)
    const float* __restrict__ hrow = h + (size_t)arow * IN_F;

    // prefetch A tile + epilogue vectors (overlaps W staging + barrier)
    float4 ha[4], hb[4];
    #pragma unroll
    for (int kk = 0; kk < 4; ++kk) {
        const int ko = kk * 32 + q * 8;
        ha[kk] = *(const float4*)&hrow[ko];
        hb[kk] = *(const float4*)&hrow[ko + 4];
    }
    float bb[4], as_[4], ad_[4];
    #pragma unroll
    for (int ct = 0; ct < 4; ++ct) {
        bb[ct]  = b[ct * 16 + col];
        as_[ct] = a[ct * 16 + col];
        ad_[ct] = a[OUT_F + ct * 16 + col];
    }

    for (int i = tid * 8; i < OUT_F * IN_F; i += 2048) {
        int f = i >> 7, k = i & 127;
        float4 va = *(const float4*)&W[i];
        float4 vb = *(const float4*)&W[i + 4];
        *(h8*)&wsh[f * HS + k] = cvt8(va, vb);
    }
    __syncthreads();

    f4 acc[4] = {{0.f,0.f,0.f,0.f},{0.f,0.f,0.f,0.f},
                 {0.f,0.f,0.f,0.f},{0.f,0.f,0.f,0.f}};
    #pragma unroll
    for (int kk = 0; kk < 4; ++kk) {
        const int ko = kk * 32 + q * 8;
        h8 av = cvt8(ha[kk], hb[kk]);
        #pragma unroll
        for (int ct = 0; ct < 4; ++ct) {
            h8 bv = *(const h8*)&wsh[(ct * 16 + col) * HS + ko];
            acc[ct] = __builtin_amdgcn_mfma_f32_16x16x32_f16(av, bv, acc[ct], 0, 0, 0);
        }
    }

    #pragma unroll
    for (int reg = 0; reg < 4; ++reg) {
        int n = node0 + r0 + q * 4 + reg;   // C row = node
        float vv[4], ps = 0.f, pd = 0.f;
        #pragma unroll
        for (int ct = 0; ct < 4; ++ct) {
            float v = acc[ct][reg] + bb[ct];
            vv[ct] = v;
            ps = fmaf(v, as_[ct], ps);
            pd = fmaf(v, ad_[ct], pd);
        }
        #pragma unroll
        for (int m = 1; m <= 8; m <<= 1) {
            ps += __shfl_xor(ps, m, 64);
            pd += __shfl_xor(pd, m, 64);
        }
        if (n < n_nodes) {
            size_t base = (size_t)n * OUT_F + col;
            #pragma unroll
            for (int ct = 0; ct < 4; ++ct)
                data_h[base + ct * 16] = (_Float16)vv[ct];
            if (col == 0) { s_src[n] = ps; s_dst[n] = pd; }
        }
    }
}

// ---------------------------------------------------------------------------
// Pass 2 (fused sort + gather), one block per 64-src SUB-BIN.
// Sort phase: weight computed with 512 flat threads; stored packed {dst, w}
// as uint2 at a per-node ROTATED slot ((r + 2*(nl&7)) & 63) so gather reads
// are bank-conflict-free. pk reads nontemporal (streaming).
// R19: DEGREE-SORTED node->group assignment. A wave processes its 8 nodes
// in lockstep, so its iteration count is max(deg of 8). Random assignment:
// E[max of 8 Poi(16)] ~ 23 vs mean 16 -> ~40% masked-lane waste. Rank-sort
// the 64 nodes by degree (64-thread O(64^2), ~200 cy) and give wave w ranks
// 8w..8w+7 -> max-in-wave ~ mean-in-wave; total gather iterations drop
// ~1.4x -> ~1.05x of optimal. Waves are barrier-free after sort; the
// big-degree wave's tail is backfilled from other resident blocks.
// Gather phase: one node per 8-lane group, lane owns a feature octet;
// no cross-lane ops; 8 independent gather chains per wave, x4 unroll.
// ---------------------------------------------------------------------------
__global__ __launch_bounds__(512) void k_bin(
    const unsigned* __restrict__ pk, const int* __restrict__ gcur,
    const float* __restrict__ s_src, const float* __restrict__ s_dst,
    const _Float16* __restrict__ data_h, float* __restrict__ out, int n_nodes)
{
    __shared__ uint2 edl[64 * CAP];   // 32768 B: {dst, w-bits}, rotated slots
    __shared__ int   lcnt[64];
    __shared__ int   nsort[64];       // rank -> local node, desc degree
    __shared__ float ssl[64];
    const int sub  = (int)blockIdx.x;
    const int tid  = threadIdx.x;
    const int nbase = sub * SUBSZ;

    if (tid < 64) {
        lcnt[tid] = 0;
        int n = nbase + tid;
        ssl[tid] = (n < n_nodes) ? s_src[n] : 0.f;
    }
    __syncthreads();

    const int ecnt = min(gcur[sub], CAPH);
    for (int i = tid; i < ecnt; i += 512) {
        unsigned v = __builtin_nontemporal_load(&pk[(size_t)sub * CAPH + i]);
        int s63 = (int)(v >> 16);
        int d = (int)(v & 0xffffu);
        float w = edge_w(ssl[s63] + s_dst[d]);
        int r = atomicAdd(&lcnt[s63], 1);
        if (r < CAP) {
            uint2 e; e.x = (unsigned)d; e.y = __float_as_uint(w);
            edl[s63 * CAP + ((r + 2 * (s63 & 7)) & (CAP - 1))] = e;
        }
    }
    __syncthreads();

    // degree rank sort (desc, tie-break by index): bijective rank -> nsort
    if (tid < 64) {
        int my = lcnt[tid];
        int r = 0;
        #pragma unroll 8
        for (int j = 0; j < 64; ++j) {
            int dj = lcnt[j];
            r += (dj > my) || (dj == my && j < tid);
        }
        nsort[r] = tid;
    }
    __syncthreads();

    const int wv = tid >> 6, lane = tid & 63;   // 8 waves
    const int g  = lane >> 3;      // node sub-index within wave
    const int fl = lane & 7;       // feature octet
    const int nl = nsort[wv * 8 + g];   // local node, degree-balanced
    const int n  = nbase + nl;
    const int rot = 2 * (nl & 7);  // bucket slot rotation (matches writer)
    const int cn = (n < n_nodes) ? min(lcnt[nl], CAP) : 0;
    const int bbase = nl * CAP;

    float ac[8] = {0.f,0.f,0.f,0.f,0.f,0.f,0.f,0.f};
    float rs = 0.f;
    int t = 0;
    for (; t + 4 <= cn; t += 4) {
        uint2 e0 = edl[bbase + ((t + 0 + rot) & (CAP - 1))];
        uint2 e1 = edl[bbase + ((t + 1 + rot) & (CAP - 1))];
        uint2 e2 = edl[bbase + ((t + 2 + rot) & (CAP - 1))];
        uint2 e3 = edl[bbase + ((t + 3 + rot) & (CAP - 1))];
        h8 x0 = *(const h8*)&data_h[(size_t)e0.x * OUT_F + 8 * fl];
        h8 x1 = *(const h8*)&data_h[(size_t)e1.x * OUT_F + 8 * fl];
        h8 x2 = *(const h8*)&data_h[(size_t)e2.x * OUT_F + 8 * fl];
        h8 x3 = *(const h8*)&data_h[(size_t)e3.x * OUT_F + 8 * fl];
        float w0 = __uint_as_float(e0.y);
        float w1 = __uint_as_float(e1.y);
        float w2 = __uint_as_float(e2.y);
        float w3 = __uint_as_float(e3.y);
        #pragma unroll
        for (int i = 0; i < 8; ++i) ac[i] = fmaf(w0, (float)x0[i], ac[i]);
        #pragma unroll
        for (int i = 0; i < 8; ++i) ac[i] = fmaf(w1, (float)x1[i], ac[i]);
        #pragma unroll
        for (int i = 0; i < 8; ++i) ac[i] = fmaf(w2, (float)x2[i], ac[i]);
        #pragma unroll
        for (int i = 0; i < 8; ++i) ac[i] = fmaf(w3, (float)x3[i], ac[i]);
        rs += (w0 + w1) + (w2 + w3);
    }
    for (; t < cn; ++t) {
        uint2 e0 = edl[bbase + ((t + rot) & (CAP - 1))];
        float w0 = __uint_as_float(e0.y);
        h8 x0 = *(const h8*)&data_h[(size_t)e0.x * OUT_F + 8 * fl];
        #pragma unroll
        for (int i = 0; i < 8; ++i) ac[i] = fmaf(w0, (float)x0[i], ac[i]);
        rs += w0;
    }

    if (n < n_nodes) {
        size_t o = (size_t)n * OUT_F + 8 * fl;
        f4 r0, r1;
        if (rs == 0.f) {
            h8 xv = *(const h8*)&data_h[o];
            r0[0] = (float)xv[0]; r0[1] = (float)xv[1];
            r0[2] = (float)xv[2]; r0[3] = (float)xv[3];
            r1[0] = (float)xv[4]; r1[1] = (float)xv[5];
            r1[2] = (float)xv[6]; r1[7 - 7] = r1[0]; // no-op keep layout clear
            r1[0] = (float)xv[4]; r1[1] = (float)xv[5];
            r1[2] = (float)xv[6]; r1[3] = (float)xv[7];
        } else {
            float inv = 1.f / rs;
            r0[0] = ac[0] * inv; r0[1] = ac[1] * inv;
            r0[2] = ac[2] * inv; r0[3] = ac[3] * inv;
            r1[0] = ac[4] * inv; r1[1] = ac[5] * inv;
            r1[2] = ac[6] * inv; r1[3] = ac[7] * inv;
        }
        __builtin_nontemporal_store(r0, (f4*)&out[o]);
        __builtin_nontemporal_store(r1, (f4*)&out[o + 4]);
    }
}

extern "C" void kernel_launch(void* const* d_in, const int* in_sizes, int n_in,
                              void* d_out, int out_size, void* d_ws, size_t ws_size,
                              hipStream_t stream)
{
    const float* h   = (const float*)d_in[0];
    const int*   adj = (const int*)  d_in[1];   // (2,E) int32
    const float* W   = (const float*)d_in[2];
    const float* b   = (const float*)d_in[3];
    const float* a   = (const float*)d_in[4];
    float* out = (float*)d_out;

    const int n_nodes = in_sizes[0] / IN_F;
    const int n_edges = in_sizes[1] / 2;
    const int* src = adj;
    const int* dst = adj + n_edges;
    const int nsub = (n_nodes + SUBSZ - 1) >> SUBSH;

    // ws: data_h f16[N*64] | pk u32[nsub*CAPH] | s_src f32[N] | s_dst f32[N]
    //   | gcur i32[nsub]
    char* p = (char*)d_ws;
    _Float16*       data_h = (_Float16*)p;       p += (size_t)n_nodes * OUT_F * 2;
    unsigned*       pk     = (unsigned*)p;       p += (size_t)nsub * CAPH * 4;
    float*          s_src  = (float*)p;          p += (size_t)n_nodes * 4;
    float*          s_dst  = (float*)p;          p += (size_t)n_nodes * 4;
    int*            gcur   = (int*)p;            p += (size_t)nsub * 4;

    (void)hipMemsetAsync(gcur, 0, (size_t)nsub * sizeof(int), stream);

    const int g_p1  = (n_edges + 4095) / 4096;
    const int g_lin = (n_nodes + 63) / 64;
    k_p1<<<g_p1 + g_lin, 256, 0, stream>>>(
        h, W, b, a, src, dst, gcur, pk, data_h, s_src, s_dst,
        n_nodes, n_edges, g_p1);

    k_bin<<<nsub, 512, 0, stream>>>(
        pk, gcur, s_src, s_dst, data_h, out, n_nodes);
}

// Round 8
// 118.400 us; speedup vs baseline: 1.1353x; 1.1353x over previous
//
#include <hip/hip_runtime.h>
#include <math.h>

#define IN_F 128
#define OUT_F 64
#define ALPHA 0.2f
#define INV_SQRT_F 0.125f   // 1/sqrt(OUT_F)
#define CAP 64              // per-src bucket capacity; P(deg>64) ~ 1e-20
#define SUBSH 6             // 64 srcs per sub-bin (partition granularity = gather granularity)
#define SUBSZ 64
#define CAPH 2048           // per-sub-bin edge capacity (mean 1024, +32 sigma)
#define HS 136              // f16 LDS row stride: b128 frag reads 2-way = free

typedef _Float16 h8  __attribute__((ext_vector_type(8)));
typedef float    f4  __attribute__((ext_vector_type(4)));

__device__ __forceinline__ float edge_w(float sc) {
    float lr = sc > 0.f ? sc : ALPHA * sc;
    return __expf(lr * INV_SQRT_F);
}

__device__ __forceinline__ h8 cvt8(float4 a, float4 b) {
    h8 r;
    r[0] = (_Float16)a.x; r[1] = (_Float16)a.y;
    r[2] = (_Float16)a.z; r[3] = (_Float16)a.w;
    r[4] = (_Float16)b.x; r[5] = (_Float16)b.y;
    r[6] = (_Float16)b.z; r[7] = (_Float16)b.w;
    return r;
}

// ---------------------------------------------------------------------------
// Pass 1 (block-specialized):
//   blocks [0, g_p1): edge partition by src>>6 (64-src sub-bins, 1:1 with
//     k_bin blocks). LDS histogram -> one device atomic per touched sub-bin
//     -> packed (srclow<<16|dst) chunks. R21: NO nontemporal on pk/src/dst
//     -- pk is producer->consumer via L2; nt scatter stores caused ~20us
//     regression (write amplification + L2 misses in k_bin).
//   blocks [g_p1, ...): MFMA f16 GEMM, 64 nodes/block, A-tile + epilogue
//     vectors prefetched before the W-stage barrier.
// ---------------------------------------------------------------------------
__global__ __launch_bounds__(256, 4) void k_p1(
    const float* __restrict__ h, const float* __restrict__ W,
    const float* __restrict__ b, const float* __restrict__ a,
    const int* __restrict__ src, const int* __restrict__ dst,
    int* __restrict__ gcur, unsigned* __restrict__ pk,
    _Float16* __restrict__ data_h,
    float* __restrict__ s_src, float* __restrict__ s_dst,
    int n_nodes, int n_edges, int g_p1)
{
    __shared__ _Float16 wsh[OUT_F * HS];   // 17408 B
    __shared__ int hist[1024];
    __shared__ int off[1024];
    const int tid = threadIdx.x;

    if ((int)blockIdx.x < g_p1) {
        // ---- partition part ----
        const int nsub = (n_nodes + SUBSZ - 1) >> SUBSH;
        const int e0 = (int)blockIdx.x * 4096 + tid * 16;

        for (int i = tid; i < nsub; i += 256) hist[i] = 0;
        __syncthreads();

        int s[16], d[16];
        const bool full = (e0 + 16 <= n_edges);
        if (full) {
            #pragma unroll
            for (int c = 0; c < 4; ++c) {
                int4 s4 = *(const int4*)&src[e0 + c * 4];
                int4 d4 = *(const int4*)&dst[e0 + c * 4];
                s[c*4+0] = s4.x; s[c*4+1] = s4.y; s[c*4+2] = s4.z; s[c*4+3] = s4.w;
                d[c*4+0] = d4.x; d[c*4+1] = d4.y; d[c*4+2] = d4.z; d[c*4+3] = d4.w;
            }
            #pragma unroll
            for (int i = 0; i < 16; ++i)
                atomicAdd(&hist[s[i] >> SUBSH], 1);
        } else {
            #pragma unroll
            for (int i = 0; i < 16; ++i) {
                int e = e0 + i;
                s[i] = (e < n_edges) ? src[e] : -1;
                d[i] = (e < n_edges) ? dst[e] : 0;
                if (s[i] >= 0) atomicAdd(&hist[s[i] >> SUBSH], 1);
            }
        }
        __syncthreads();

        for (int i = tid; i < nsub; i += 256) {
            int c = hist[i];
            off[i] = (c > 0) ? atomicAdd(&gcur[i], c) : 0;
            hist[i] = 0;
        }
        __syncthreads();

        #pragma unroll
        for (int i = 0; i < 16; ++i) {
            if (s[i] < 0) continue;
            int sub = s[i] >> SUBSH;
            int r = atomicAdd(&hist[sub], 1);
            int p = off[sub] + r;
            if (p < CAPH)
                pk[(size_t)sub * CAPH + p] =
                    ((unsigned)(s[i] & (SUBSZ - 1)) << 16) | (unsigned)d[i];
        }
        return;
    }

    // ---- GEMM part: 64 nodes per block, A prefetched before W stage ----
    const int node0 = ((int)blockIdx.x - g_p1) * 64;

    const int wv  = tid >> 6;
    const int lane = tid & 63;
    const int q   = lane >> 4;     // quad
    const int col = lane & 15;
    const int r0  = wv * 16;

    const int arow = min(node0 + r0 + col, n_nodes - 1);   // A row (node)
    const float* __restrict__ hrow = h + (size_t)arow * IN_F;

    // prefetch A tile + epilogue vectors (overlaps W staging + barrier)
    float4 ha[4], hb[4];
    #pragma unroll
    for (int kk = 0; kk < 4; ++kk) {
        const int ko = kk * 32 + q * 8;
        ha[kk] = *(const float4*)&hrow[ko];
        hb[kk] = *(const float4*)&hrow[ko + 4];
    }
    float bb[4], as_[4], ad_[4];
    #pragma unroll
    for (int ct = 0; ct < 4; ++ct) {
        bb[ct]  = b[ct * 16 + col];
        as_[ct] = a[ct * 16 + col];
        ad_[ct] = a[OUT_F + ct * 16 + col];
    }

    for (int i = tid * 8; i < OUT_F * IN_F; i += 2048) {
        int f = i >> 7, k = i & 127;
        float4 va = *(const float4*)&W[i];
        float4 vb = *(const float4*)&W[i + 4];
        *(h8*)&wsh[f * HS + k] = cvt8(va, vb);
    }
    __syncthreads();

    f4 acc[4] = {{0.f,0.f,0.f,0.f},{0.f,0.f,0.f,0.f},
                 {0.f,0.f,0.f,0.f},{0.f,0.f,0.f,0.f}};
    #pragma unroll
    for (int kk = 0; kk < 4; ++kk) {
        const int ko = kk * 32 + q * 8;
        h8 av = cvt8(ha[kk], hb[kk]);
        #pragma unroll
        for (int ct = 0; ct < 4; ++ct) {
            h8 bv = *(const h8*)&wsh[(ct * 16 + col) * HS + ko];
            acc[ct] = __builtin_amdgcn_mfma_f32_16x16x32_f16(av, bv, acc[ct], 0, 0, 0);
        }
    }

    #pragma unroll
    for (int reg = 0; reg < 4; ++reg) {
        int n = node0 + r0 + q * 4 + reg;   // C row = node
        float vv[4], ps = 0.f, pd = 0.f;
        #pragma unroll
        for (int ct = 0; ct < 4; ++ct) {
            float v = acc[ct][reg] + bb[ct];
            vv[ct] = v;
            ps = fmaf(v, as_[ct], ps);
            pd = fmaf(v, ad_[ct], pd);
        }
        #pragma unroll
        for (int m = 1; m <= 8; m <<= 1) {
            ps += __shfl_xor(ps, m, 64);
            pd += __shfl_xor(pd, m, 64);
        }
        if (n < n_nodes) {
            size_t base = (size_t)n * OUT_F + col;
            #pragma unroll
            for (int ct = 0; ct < 4; ++ct)
                data_h[base + ct * 16] = (_Float16)vv[ct];
            if (col == 0) { s_src[n] = ps; s_dst[n] = pd; }
        }
    }
}

// ---------------------------------------------------------------------------
// Pass 2 (fused sort + gather), one block per 64-src SUB-BIN.
// Sort phase: weight computed with 512 flat threads; stored packed {dst, w}
// as uint2 at a per-node ROTATED slot ((r + 2*(nl&7)) & 63) so gather reads
// are bank-conflict-free. pk reads through L2 (written by k_p1; NO nt).
// Degree-sorted node->group assignment (kept from R19): rank-sort the 64
// nodes by degree; wave w takes ranks 8w..8w+7. Concentrates heavy nodes
// so light waves finish early and the CU backfills from other blocks;
// reduces total masked-lane work. Block latency still ~max-degree wave.
// Gather phase: one node per 8-lane group, lane owns a feature octet;
// no cross-lane ops; 8 independent gather chains per wave, x4 unroll.
// ---------------------------------------------------------------------------
__global__ __launch_bounds__(512) void k_bin(
    const unsigned* __restrict__ pk, const int* __restrict__ gcur,
    const float* __restrict__ s_src, const float* __restrict__ s_dst,
    const _Float16* __restrict__ data_h, float* __restrict__ out, int n_nodes)
{
    __shared__ uint2 edl[64 * CAP];   // 32768 B: {dst, w-bits}, rotated slots
    __shared__ int   lcnt[64];
    __shared__ int   nsort[64];       // rank -> local node, desc degree
    __shared__ float ssl[64];
    const int sub  = (int)blockIdx.x;
    const int tid  = threadIdx.x;
    const int nbase = sub * SUBSZ;

    if (tid < 64) {
        lcnt[tid] = 0;
        int n = nbase + tid;
        ssl[tid] = (n < n_nodes) ? s_src[n] : 0.f;
    }
    __syncthreads();

    const int ecnt = min(gcur[sub], CAPH);
    for (int i = tid; i < ecnt; i += 512) {
        unsigned v = pk[(size_t)sub * CAPH + i];
        int s63 = (int)(v >> 16);
        int d = (int)(v & 0xffffu);
        float w = edge_w(ssl[s63] + s_dst[d]);
        int r = atomicAdd(&lcnt[s63], 1);
        if (r < CAP) {
            uint2 e; e.x = (unsigned)d; e.y = __float_as_uint(w);
            edl[s63 * CAP + ((r + 2 * (s63 & 7)) & (CAP - 1))] = e;
        }
    }
    __syncthreads();

    // degree rank sort (desc, tie-break by index): bijective rank -> nsort
    if (tid < 64) {
        int my = lcnt[tid];
        int r = 0;
        #pragma unroll 8
        for (int j = 0; j < 64; ++j) {
            int dj = lcnt[j];
            r += (dj > my) || (dj == my && j < tid);
        }
        nsort[r] = tid;
    }
    __syncthreads();

    const int wv = tid >> 6, lane = tid & 63;   // 8 waves
    const int g  = lane >> 3;      // node sub-index within wave
    const int fl = lane & 7;       // feature octet
    const int nl = nsort[wv * 8 + g];   // local node, degree-balanced
    const int n  = nbase + nl;
    const int rot = 2 * (nl & 7);  // bucket slot rotation (matches writer)
    const int cn = (n < n_nodes) ? min(lcnt[nl], CAP) : 0;
    const int bbase = nl * CAP;

    float ac[8] = {0.f,0.f,0.f,0.f,0.f,0.f,0.f,0.f};
    float rs = 0.f;
    int t = 0;
    for (; t + 4 <= cn; t += 4) {
        uint2 e0 = edl[bbase + ((t + 0 + rot) & (CAP - 1))];
        uint2 e1 = edl[bbase + ((t + 1 + rot) & (CAP - 1))];
        uint2 e2 = edl[bbase + ((t + 2 + rot) & (CAP - 1))];
        uint2 e3 = edl[bbase + ((t + 3 + rot) & (CAP - 1))];
        h8 x0 = *(const h8*)&data_h[(size_t)e0.x * OUT_F + 8 * fl];
        h8 x1 = *(const h8*)&data_h[(size_t)e1.x * OUT_F + 8 * fl];
        h8 x2 = *(const h8*)&data_h[(size_t)e2.x * OUT_F + 8 * fl];
        h8 x3 = *(const h8*)&data_h[(size_t)e3.x * OUT_F + 8 * fl];
        float w0 = __uint_as_float(e0.y);
        float w1 = __uint_as_float(e1.y);
        float w2 = __uint_as_float(e2.y);
        float w3 = __uint_as_float(e3.y);
        #pragma unroll
        for (int i = 0; i < 8; ++i) ac[i] = fmaf(w0, (float)x0[i], ac[i]);
        #pragma unroll
        for (int i = 0; i < 8; ++i) ac[i] = fmaf(w1, (float)x1[i], ac[i]);
        #pragma unroll
        for (int i = 0; i < 8; ++i) ac[i] = fmaf(w2, (float)x2[i], ac[i]);
        #pragma unroll
        for (int i = 0; i < 8; ++i) ac[i] = fmaf(w3, (float)x3[i], ac[i]);
        rs += (w0 + w1) + (w2 + w3);
    }
    for (; t < cn; ++t) {
        uint2 e0 = edl[bbase + ((t + rot) & (CAP - 1))];
        float w0 = __uint_as_float(e0.y);
        h8 x0 = *(const h8*)&data_h[(size_t)e0.x * OUT_F + 8 * fl];
        #pragma unroll
        for (int i = 0; i < 8; ++i) ac[i] = fmaf(w0, (float)x0[i], ac[i]);
        rs += w0;
    }

    if (n < n_nodes) {
        size_t o = (size_t)n * OUT_F + 8 * fl;
        f4 r0, r1;
        if (rs == 0.f) {
            h8 xv = *(const h8*)&data_h[o];
            r0[0] = (float)xv[0]; r0[1] = (float)xv[1];
            r0[2] = (float)xv[2]; r0[3] = (float)xv[3];
            r1[0] = (float)xv[4]; r1[1] = (float)xv[5];
            r1[2] = (float)xv[6]; r1[3] = (float)xv[7];
        } else {
            float inv = 1.f / rs;
            r0[0] = ac[0] * inv; r0[1] = ac[1] * inv;
            r0[2] = ac[2] * inv; r0[3] = ac[3] * inv;
            r1[0] = ac[4] * inv; r1[1] = ac[5] * inv;
            r1[2] = ac[6] * inv; r1[3] = ac[7] * inv;
        }
        __builtin_nontemporal_store(r0, (f4*)&out[o]);
        __builtin_nontemporal_store(r1, (f4*)&out[o + 4]);
    }
}

extern "C" void kernel_launch(void* const* d_in, const int* in_sizes, int n_in,
                              void* d_out, int out_size, void* d_ws, size_t ws_size,
                              hipStream_t stream)
{
    const float* h   = (const float*)d_in[0];
    const int*   adj = (const int*)  d_in[1];   // (2,E) int32
    const float* W   = (const float*)d_in[2];
    const float* b   = (const float*)d_in[3];
    const float* a   = (const float*)d_in[4];
    float* out = (float*)d_out;

    const int n_nodes = in_sizes[0] / IN_F;
    const int n_edges = in_sizes[1] / 2;
    const int* src = adj;
    const int* dst = adj + n_edges;
    const int nsub = (n_nodes + SUBSZ - 1) >> SUBSH;

    // ws: data_h f16[N*64] | pk u32[nsub*CAPH] | s_src f32[N] | s_dst f32[N]
    //   | gcur i32[nsub]
    char* p = (char*)d_ws;
    _Float16*       data_h = (_Float16*)p;       p += (size_t)n_nodes * OUT_F * 2;
    unsigned*       pk     = (unsigned*)p;       p += (size_t)nsub * CAPH * 4;
    float*          s_src  = (float*)p;          p += (size_t)n_nodes * 4;
    float*          s_dst  = (float*)p;          p += (size_t)n_nodes * 4;
    int*            gcur   = (int*)p;            p += (size_t)nsub * 4;

    (void)hipMemsetAsync(gcur, 0, (size_t)nsub * sizeof(int), stream);

    const int g_p1  = (n_edges + 4095) / 4096;
    const int g_lin = (n_nodes + 63) / 64;
    k_p1<<<g_p1 + g_lin, 256, 0, stream>>>(
        h, W, b, a, src, dst, gcur, pk, data_h, s_src, s_dst,
        n_nodes, n_edges, g_p1);

    k_bin<<<nsub, 512, 0, stream>>>(
        pk, gcur, s_src, s_dst, data_h, out, n_nodes);
}

// Round 9
// 113.859 us; speedup vs baseline: 1.1806x; 1.0399x over previous
//
#include <hip/hip_runtime.h>
#include <math.h>

#define IN_F 128
#define OUT_F 64
#define ALPHA 0.2f
#define INV_SQRT_F 0.125f   // 1/sqrt(OUT_F)
#define CAP 64              // per-src bucket capacity; P(deg>64) ~ 1e-20
#define SUBSH 6             // 64 srcs per sub-bin (partition granularity = gather granularity)
#define SUBSZ 64
#define CAPH 2048           // per-sub-bin edge capacity (mean 1024, +32 sigma)
#define HS 136              // f16 LDS row stride: b128 frag reads 2-way = free

typedef _Float16 h8  __attribute__((ext_vector_type(8)));
typedef float    f4  __attribute__((ext_vector_type(4)));

__device__ __forceinline__ float edge_w(float sc) {
    float lr = sc > 0.f ? sc : ALPHA * sc;
    return __expf(lr * INV_SQRT_F);
}

__device__ __forceinline__ h8 cvt8(float4 a, float4 b) {
    h8 r;
    r[0] = (_Float16)a.x; r[1] = (_Float16)a.y;
    r[2] = (_Float16)a.z; r[3] = (_Float16)a.w;
    r[4] = (_Float16)b.x; r[5] = (_Float16)b.y;
    r[6] = (_Float16)b.z; r[7] = (_Float16)b.w;
    return r;
}

// ---------------------------------------------------------------------------
// Pass 1 (block-specialized):
//   blocks [0, g_p1): edge partition by src>>6 (64-src sub-bins, 1:1 with
//     k_bin blocks). LDS histogram -> one device atomic per touched sub-bin
//     -> packed (srclow<<16|dst) chunks. All pk/src/dst traffic through L2
//     (nontemporal hints on producer->consumer data cost ~20us, R20).
//   blocks [g_p1, ...): MFMA f16 GEMM, 64 nodes/block, A-tile + epilogue
//     vectors prefetched before the W-stage barrier.
// ---------------------------------------------------------------------------
__global__ __launch_bounds__(256, 4) void k_p1(
    const float* __restrict__ h, const float* __restrict__ W,
    const float* __restrict__ b, const float* __restrict__ a,
    const int* __restrict__ src, const int* __restrict__ dst,
    int* __restrict__ gcur, unsigned* __restrict__ pk,
    _Float16* __restrict__ data_h,
    float* __restrict__ s_src, float* __restrict__ s_dst,
    int n_nodes, int n_edges, int g_p1)
{
    __shared__ _Float16 wsh[OUT_F * HS];   // 17408 B
    __shared__ int hist[1024];
    __shared__ int off[1024];
    const int tid = threadIdx.x;

    if ((int)blockIdx.x < g_p1) {
        // ---- partition part ----
        const int nsub = (n_nodes + SUBSZ - 1) >> SUBSH;
        const int e0 = (int)blockIdx.x * 4096 + tid * 16;

        for (int i = tid; i < nsub; i += 256) hist[i] = 0;
        __syncthreads();

        int s[16], d[16];
        const bool full = (e0 + 16 <= n_edges);
        if (full) {
            #pragma unroll
            for (int c = 0; c < 4; ++c) {
                int4 s4 = *(const int4*)&src[e0 + c * 4];
                int4 d4 = *(const int4*)&dst[e0 + c * 4];
                s[c*4+0] = s4.x; s[c*4+1] = s4.y; s[c*4+2] = s4.z; s[c*4+3] = s4.w;
                d[c*4+0] = d4.x; d[c*4+1] = d4.y; d[c*4+2] = d4.z; d[c*4+3] = d4.w;
            }
            #pragma unroll
            for (int i = 0; i < 16; ++i)
                atomicAdd(&hist[s[i] >> SUBSH], 1);
        } else {
            #pragma unroll
            for (int i = 0; i < 16; ++i) {
                int e = e0 + i;
                s[i] = (e < n_edges) ? src[e] : -1;
                d[i] = (e < n_edges) ? dst[e] : 0;
                if (s[i] >= 0) atomicAdd(&hist[s[i] >> SUBSH], 1);
            }
        }
        __syncthreads();

        for (int i = tid; i < nsub; i += 256) {
            int c = hist[i];
            off[i] = (c > 0) ? atomicAdd(&gcur[i], c) : 0;
            hist[i] = 0;
        }
        __syncthreads();

        #pragma unroll
        for (int i = 0; i < 16; ++i) {
            if (s[i] < 0) continue;
            int sub = s[i] >> SUBSH;
            int r = atomicAdd(&hist[sub], 1);
            int p = off[sub] + r;
            if (p < CAPH)
                pk[(size_t)sub * CAPH + p] =
                    ((unsigned)(s[i] & (SUBSZ - 1)) << 16) | (unsigned)d[i];
        }
        return;
    }

    // ---- GEMM part: 64 nodes per block, A prefetched before W stage ----
    const int node0 = ((int)blockIdx.x - g_p1) * 64;

    const int wv  = tid >> 6;
    const int lane = tid & 63;
    const int q   = lane >> 4;     // quad
    const int col = lane & 15;
    const int r0  = wv * 16;

    const int arow = min(node0 + r0 + col, n_nodes - 1);   // A row (node)
    const float* __restrict__ hrow = h + (size_t)arow * IN_F;

    // prefetch A tile + epilogue vectors (overlaps W staging + barrier)
    float4 ha[4], hb[4];
    #pragma unroll
    for (int kk = 0; kk < 4; ++kk) {
        const int ko = kk * 32 + q * 8;
        ha[kk] = *(const float4*)&hrow[ko];
        hb[kk] = *(const float4*)&hrow[ko + 4];
    }
    float bb[4], as_[4], ad_[4];
    #pragma unroll
    for (int ct = 0; ct < 4; ++ct) {
        bb[ct]  = b[ct * 16 + col];
        as_[ct] = a[ct * 16 + col];
        ad_[ct] = a[OUT_F + ct * 16 + col];
    }

    for (int i = tid * 8; i < OUT_F * IN_F; i += 2048) {
        int f = i >> 7, k = i & 127;
        float4 va = *(const float4*)&W[i];
        float4 vb = *(const float4*)&W[i + 4];
        *(h8*)&wsh[f * HS + k] = cvt8(va, vb);
    }
    __syncthreads();

    f4 acc[4] = {{0.f,0.f,0.f,0.f},{0.f,0.f,0.f,0.f},
                 {0.f,0.f,0.f,0.f},{0.f,0.f,0.f,0.f}};
    #pragma unroll
    for (int kk = 0; kk < 4; ++kk) {
        const int ko = kk * 32 + q * 8;
        h8 av = cvt8(ha[kk], hb[kk]);
        #pragma unroll
        for (int ct = 0; ct < 4; ++ct) {
            h8 bv = *(const h8*)&wsh[(ct * 16 + col) * HS + ko];
            acc[ct] = __builtin_amdgcn_mfma_f32_16x16x32_f16(av, bv, acc[ct], 0, 0, 0);
        }
    }

    #pragma unroll
    for (int reg = 0; reg < 4; ++reg) {
        int n = node0 + r0 + q * 4 + reg;   // C row = node
        float vv[4], ps = 0.f, pd = 0.f;
        #pragma unroll
        for (int ct = 0; ct < 4; ++ct) {
            float v = acc[ct][reg] + bb[ct];
            vv[ct] = v;
            ps = fmaf(v, as_[ct], ps);
            pd = fmaf(v, ad_[ct], pd);
        }
        #pragma unroll
        for (int m = 1; m <= 8; m <<= 1) {
            ps += __shfl_xor(ps, m, 64);
            pd += __shfl_xor(pd, m, 64);
        }
        if (n < n_nodes) {
            size_t base = (size_t)n * OUT_F + col;
            #pragma unroll
            for (int ct = 0; ct < 4; ++ct)
                data_h[base + ct * 16] = (_Float16)vv[ct];
            if (col == 0) { s_src[n] = ps; s_dst[n] = pd; }
        }
    }
}

// ---------------------------------------------------------------------------
// Pass 2 (fused sort + gather), one block per 64-src SUB-BIN.
// Sort phase: weight computed with 512 flat threads; stored packed {dst, w}
// as uint2 at a per-node ROTATED slot ((r + 2*(nl&7)) & 63).
// Gather phase: one node per 8-lane group with nl = wv*8+g -- this IS the
// bank-conflict-free guarantee: the 8 groups of a wave have distinct nl&7,
// hence distinct rotations 0,2,..,14 -> distinct bank pairs at each t.
// (R21's degree-sorted nl broke this invariant -> birthday collisions in
// nl&7 -> ~2x LDS conflicts in the hot loop -> +5us. Reverted.)
// Lane owns a feature octet; no cross-lane ops; 8 independent gather
// chains per wave, x4 unroll.
// ---------------------------------------------------------------------------
__global__ __launch_bounds__(512) void k_bin(
    const unsigned* __restrict__ pk, const int* __restrict__ gcur,
    const float* __restrict__ s_src, const float* __restrict__ s_dst,
    const _Float16* __restrict__ data_h, float* __restrict__ out, int n_nodes)
{
    __shared__ uint2 edl[64 * CAP];   // 32768 B: {dst, w-bits}, rotated slots
    __shared__ int   lcnt[64];
    __shared__ float ssl[64];
    const int sub  = (int)blockIdx.x;
    const int tid  = threadIdx.x;
    const int nbase = sub * SUBSZ;

    if (tid < 64) {
        lcnt[tid] = 0;
        int n = nbase + tid;
        ssl[tid] = (n < n_nodes) ? s_src[n] : 0.f;
    }
    __syncthreads();

    const int ecnt = min(gcur[sub], CAPH);
    for (int i = tid; i < ecnt; i += 512) {
        unsigned v = pk[(size_t)sub * CAPH + i];
        int s63 = (int)(v >> 16);
        int d = (int)(v & 0xffffu);
        float w = edge_w(ssl[s63] + s_dst[d]);
        int r = atomicAdd(&lcnt[s63], 1);
        if (r < CAP) {
            uint2 e; e.x = (unsigned)d; e.y = __float_as_uint(w);
            edl[s63 * CAP + ((r + 2 * (s63 & 7)) & (CAP - 1))] = e;
        }
    }
    __syncthreads();

    const int wv = tid >> 6, lane = tid & 63;   // 8 waves
    const int g  = lane >> 3;      // node sub-index within wave
    const int fl = lane & 7;       // feature octet
    const int nl = wv * 8 + g;     // local node 0..63 (distinct nl&7 per wave)
    const int n  = nbase + nl;
    const int rot = 2 * (nl & 7);  // bucket slot rotation (matches writer)
    const int cn = (n < n_nodes) ? min(lcnt[nl], CAP) : 0;
    const int bbase = nl * CAP;

    float ac[8] = {0.f,0.f,0.f,0.f,0.f,0.f,0.f,0.f};
    float rs = 0.f;
    int t = 0;
    for (; t + 4 <= cn; t += 4) {
        uint2 e0 = edl[bbase + ((t + 0 + rot) & (CAP - 1))];
        uint2 e1 = edl[bbase + ((t + 1 + rot) & (CAP - 1))];
        uint2 e2 = edl[bbase + ((t + 2 + rot) & (CAP - 1))];
        uint2 e3 = edl[bbase + ((t + 3 + rot) & (CAP - 1))];
        h8 x0 = *(const h8*)&data_h[(size_t)e0.x * OUT_F + 8 * fl];
        h8 x1 = *(const h8*)&data_h[(size_t)e1.x * OUT_F + 8 * fl];
        h8 x2 = *(const h8*)&data_h[(size_t)e2.x * OUT_F + 8 * fl];
        h8 x3 = *(const h8*)&data_h[(size_t)e3.x * OUT_F + 8 * fl];
        float w0 = __uint_as_float(e0.y);
        float w1 = __uint_as_float(e1.y);
        float w2 = __uint_as_float(e2.y);
        float w3 = __uint_as_float(e3.y);
        #pragma unroll
        for (int i = 0; i < 8; ++i) ac[i] = fmaf(w0, (float)x0[i], ac[i]);
        #pragma unroll
        for (int i = 0; i < 8; ++i) ac[i] = fmaf(w1, (float)x1[i], ac[i]);
        #pragma unroll
        for (int i = 0; i < 8; ++i) ac[i] = fmaf(w2, (float)x2[i], ac[i]);
        #pragma unroll
        for (int i = 0; i < 8; ++i) ac[i] = fmaf(w3, (float)x3[i], ac[i]);
        rs += (w0 + w1) + (w2 + w3);
    }
    for (; t < cn; ++t) {
        uint2 e0 = edl[bbase + ((t + rot) & (CAP - 1))];
        float w0 = __uint_as_float(e0.y);
        h8 x0 = *(const h8*)&data_h[(size_t)e0.x * OUT_F + 8 * fl];
        #pragma unroll
        for (int i = 0; i < 8; ++i) ac[i] = fmaf(w0, (float)x0[i], ac[i]);
        rs += w0;
    }

    if (n < n_nodes) {
        size_t o = (size_t)n * OUT_F + 8 * fl;
        f4 r0, r1;
        if (rs == 0.f) {
            h8 xv = *(const h8*)&data_h[o];
            r0[0] = (float)xv[0]; r0[1] = (float)xv[1];
            r0[2] = (float)xv[2]; r0[3] = (float)xv[3];
            r1[0] = (float)xv[4]; r1[1] = (float)xv[5];
            r1[2] = (float)xv[6]; r1[3] = (float)xv[7];
        } else {
            float inv = 1.f / rs;
            r0[0] = ac[0] * inv; r0[1] = ac[1] * inv;
            r0[2] = ac[2] * inv; r0[3] = ac[3] * inv;
            r1[0] = ac[4] * inv; r1[1] = ac[5] * inv;
            r1[2] = ac[6] * inv; r1[3] = ac[7] * inv;
        }
        __builtin_nontemporal_store(r0, (f4*)&out[o]);
        __builtin_nontemporal_store(r1, (f4*)&out[o + 4]);
    }
}

extern "C" void kernel_launch(void* const* d_in, const int* in_sizes, int n_in,
                              void* d_out, int out_size, void* d_ws, size_t ws_size,
                              hipStream_t stream)
{
    const float* h   = (const float*)d_in[0];
    const int*   adj = (const int*)  d_in[1];   // (2,E) int32
    const float* W   = (const float*)d_in[2];
    const float* b   = (const float*)d_in[3];
    const float* a   = (const float*)d_in[4];
    float* out = (float*)d_out;

    const int n_nodes = in_sizes[0] / IN_F;
    const int n_edges = in_sizes[1] / 2;
    const int* src = adj;
    const int* dst = adj + n_edges;
    const int nsub = (n_nodes + SUBSZ - 1) >> SUBSH;

    // ws: data_h f16[N*64] | pk u32[nsub*CAPH] | s_src f32[N] | s_dst f32[N]
    //   | gcur i32[nsub]
    char* p = (char*)d_ws;
    _Float16*       data_h = (_Float16*)p;       p += (size_t)n_nodes * OUT_F * 2;
    unsigned*       pk     = (unsigned*)p;       p += (size_t)nsub * CAPH * 4;
    float*          s_src  = (float*)p;          p += (size_t)n_nodes * 4;
    float*          s_dst  = (float*)p;          p += (size_t)n_nodes * 4;
    int*            gcur   = (int*)p;            p += (size_t)nsub * 4;

    (void)hipMemsetAsync(gcur, 0, (size_t)nsub * sizeof(int), stream);

    const int g_p1  = (n_edges + 4095) / 4096;
    const int g_lin = (n_nodes + 63) / 64;
    k_p1<<<g_p1 + g_lin, 256, 0, stream>>>(
        h, W, b, a, src, dst, gcur, pk, data_h, s_src, s_dst,
        n_nodes, n_edges, g_p1);

    k_bin<<<nsub, 512, 0, stream>>>(
        pk, gcur, s_src, s_dst, data_h, out, n_nodes);
}

// Round 10
// 112.932 us; speedup vs baseline: 1.1903x; 1.0082x over previous
//
#include <hip/hip_runtime.h>
#include <math.h>

#define IN_F 128
#define OUT_F 64
#define ALPHA 0.2f
#define INV_SQRT_F 0.125f   // 1/sqrt(OUT_F)
#define CAP 64              // per-src bucket capacity; P(deg>64) ~ 1e-20
#define SUBSH 6             // 64 srcs per sub-bin (partition granularity = gather granularity)
#define SUBSZ 64
#define CAPH 2048           // per-sub-bin edge capacity (mean 1024, +32 sigma)
#define HS 136              // f16 LDS row stride: b128 frag reads 2-way = free

typedef _Float16 h8  __attribute__((ext_vector_type(8)));
typedef float    f4  __attribute__((ext_vector_type(4)));

__device__ __forceinline__ float edge_w(float sc) {
    float lr = sc > 0.f ? sc : ALPHA * sc;
    return __expf(lr * INV_SQRT_F);
}

__device__ __forceinline__ h8 cvt8(float4 a, float4 b) {
    h8 r;
    r[0] = (_Float16)a.x; r[1] = (_Float16)a.y;
    r[2] = (_Float16)a.z; r[3] = (_Float16)a.w;
    r[4] = (_Float16)b.x; r[5] = (_Float16)b.y;
    r[6] = (_Float16)b.z; r[7] = (_Float16)b.w;
    return r;
}

// ---------------------------------------------------------------------------
// Pass 1 (block-specialized):
//   blocks [0, g_p1): edge partition by src>>6 (64-src sub-bins, 1:1 with
//     k_bin blocks). LDS histogram -> one device atomic per touched sub-bin
//     -> packed (srclow<<16|dst) chunks. All pk/src/dst traffic through L2
//     (nontemporal hints on producer->consumer data cost ~20us, R20).
//   blocks [g_p1, ...): MFMA f16 GEMM, 64 nodes/block, A-tile + epilogue
//     vectors prefetched before the W-stage barrier.
// ---------------------------------------------------------------------------
__global__ __launch_bounds__(256, 4) void k_p1(
    const float* __restrict__ h, const float* __restrict__ W,
    const float* __restrict__ b, const float* __restrict__ a,
    const int* __restrict__ src, const int* __restrict__ dst,
    int* __restrict__ gcur, unsigned* __restrict__ pk,
    _Float16* __restrict__ data_h,
    float* __restrict__ s_src, float* __restrict__ s_dst,
    int n_nodes, int n_edges, int g_p1)
{
    __shared__ _Float16 wsh[OUT_F * HS];   // 17408 B
    __shared__ int hist[1024];
    __shared__ int off[1024];
    const int tid = threadIdx.x;

    if ((int)blockIdx.x < g_p1) {
        // ---- partition part ----
        const int nsub = (n_nodes + SUBSZ - 1) >> SUBSH;
        const int e0 = (int)blockIdx.x * 4096 + tid * 16;

        for (int i = tid; i < nsub; i += 256) hist[i] = 0;
        __syncthreads();

        int s[16], d[16];
        const bool full = (e0 + 16 <= n_edges);
        if (full) {
            #pragma unroll
            for (int c = 0; c < 4; ++c) {
                int4 s4 = *(const int4*)&src[e0 + c * 4];
                int4 d4 = *(const int4*)&dst[e0 + c * 4];
                s[c*4+0] = s4.x; s[c*4+1] = s4.y; s[c*4+2] = s4.z; s[c*4+3] = s4.w;
                d[c*4+0] = d4.x; d[c*4+1] = d4.y; d[c*4+2] = d4.z; d[c*4+3] = d4.w;
            }
            #pragma unroll
            for (int i = 0; i < 16; ++i)
                atomicAdd(&hist[s[i] >> SUBSH], 1);
        } else {
            #pragma unroll
            for (int i = 0; i < 16; ++i) {
                int e = e0 + i;
                s[i] = (e < n_edges) ? src[e] : -1;
                d[i] = (e < n_edges) ? dst[e] : 0;
                if (s[i] >= 0) atomicAdd(&hist[s[i] >> SUBSH], 1);
            }
        }
        __syncthreads();

        for (int i = tid; i < nsub; i += 256) {
            int c = hist[i];
            off[i] = (c > 0) ? atomicAdd(&gcur[i], c) : 0;
            hist[i] = 0;
        }
        __syncthreads();

        #pragma unroll
        for (int i = 0; i < 16; ++i) {
            if (s[i] < 0) continue;
            int sub = s[i] >> SUBSH;
            int r = atomicAdd(&hist[sub], 1);
            int p = off[sub] + r;
            if (p < CAPH)
                pk[(size_t)sub * CAPH + p] =
                    ((unsigned)(s[i] & (SUBSZ - 1)) << 16) | (unsigned)d[i];
        }
        return;
    }

    // ---- GEMM part: 64 nodes per block, A prefetched before W stage ----
    const int node0 = ((int)blockIdx.x - g_p1) * 64;

    const int wv  = tid >> 6;
    const int lane = tid & 63;
    const int q   = lane >> 4;     // quad
    const int col = lane & 15;
    const int r0  = wv * 16;

    const int arow = min(node0 + r0 + col, n_nodes - 1);   // A row (node)
    const float* __restrict__ hrow = h + (size_t)arow * IN_F;

    // prefetch A tile + epilogue vectors (overlaps W staging + barrier)
    float4 ha[4], hb[4];
    #pragma unroll
    for (int kk = 0; kk < 4; ++kk) {
        const int ko = kk * 32 + q * 8;
        ha[kk] = *(const float4*)&hrow[ko];
        hb[kk] = *(const float4*)&hrow[ko + 4];
    }
    float bb[4], as_[4], ad_[4];
    #pragma unroll
    for (int ct = 0; ct < 4; ++ct) {
        bb[ct]  = b[ct * 16 + col];
        as_[ct] = a[ct * 16 + col];
        ad_[ct] = a[OUT_F + ct * 16 + col];
    }

    for (int i = tid * 8; i < OUT_F * IN_F; i += 2048) {
        int f = i >> 7, k = i & 127;
        float4 va = *(const float4*)&W[i];
        float4 vb = *(const float4*)&W[i + 4];
        *(h8*)&wsh[f * HS + k] = cvt8(va, vb);
    }
    __syncthreads();

    f4 acc[4] = {{0.f,0.f,0.f,0.f},{0.f,0.f,0.f,0.f},
                 {0.f,0.f,0.f,0.f},{0.f,0.f,0.f,0.f}};
    #pragma unroll
    for (int kk = 0; kk < 4; ++kk) {
        const int ko = kk * 32 + q * 8;
        h8 av = cvt8(ha[kk], hb[kk]);
        #pragma unroll
        for (int ct = 0; ct < 4; ++ct) {
            h8 bv = *(const h8*)&wsh[(ct * 16 + col) * HS + ko];
            acc[ct] = __builtin_amdgcn_mfma_f32_16x16x32_f16(av, bv, acc[ct], 0, 0, 0);
        }
    }

    #pragma unroll
    for (int reg = 0; reg < 4; ++reg) {
        int n = node0 + r0 + q * 4 + reg;   // C row = node
        float vv[4], ps = 0.f, pd = 0.f;
        #pragma unroll
        for (int ct = 0; ct < 4; ++ct) {
            float v = acc[ct][reg] + bb[ct];
            vv[ct] = v;
            ps = fmaf(v, as_[ct], ps);
            pd = fmaf(v, ad_[ct], pd);
        }
        #pragma unroll
        for (int m = 1; m <= 8; m <<= 1) {
            ps += __shfl_xor(ps, m, 64);
            pd += __shfl_xor(pd, m, 64);
        }
        if (n < n_nodes) {
            size_t base = (size_t)n * OUT_F + col;
            #pragma unroll
            for (int ct = 0; ct < 4; ++ct)
                data_h[base + ct * 16] = (_Float16)vv[ct];
            if (col == 0) { s_src[n] = ps; s_dst[n] = pd; }
        }
    }
}

// ---------------------------------------------------------------------------
// Pass 2 (fused sort + gather), one block per 64-src SUB-BIN.
// Sort phase: weight computed with 512 flat threads; stored packed {dst, w}
// as uint2 at a per-node ROTATED slot ((r + 2*(nl&7)) & 63).
// R23: RESIDUE-CLASS degree sort. Conflict-freedom only requires that the
// 8 groups of a wave hold nodes with DISTINCT nl&7 (banks 2t+4r mod 32).
// So rank-sort the 8 nodes WITHIN each residue class r=nl&7 and give wave
// w the rank-w node of class g -> wave nodes have residues 0..7 (bank-free
// preserved) AND homogeneous degree ranks. Wave-iteration sum per block
// drops ~18% (184 -> ~151 units of max-of-8 lockstep); early-finishing
// light waves backfill other resident blocks. (R21's unconstrained sort
// broke the residue invariant -> conflicts -> +5us; this keeps it.)
// Gather phase: one node per 8-lane group, lane owns a feature octet;
// no cross-lane ops; 8 independent gather chains per wave, x4 unroll.
// ---------------------------------------------------------------------------
__global__ __launch_bounds__(512) void k_bin(
    const unsigned* __restrict__ pk, const int* __restrict__ gcur,
    const float* __restrict__ s_src, const float* __restrict__ s_dst,
    const _Float16* __restrict__ data_h, float* __restrict__ out, int n_nodes)
{
    __shared__ uint2 edl[64 * CAP];   // 32768 B: {dst, w-bits}, rotated slots
    __shared__ int   lcnt[64];
    __shared__ int   nsort[64];       // nsort[rank*8 + class] = local node
    __shared__ float ssl[64];
    const int sub  = (int)blockIdx.x;
    const int tid  = threadIdx.x;
    const int nbase = sub * SUBSZ;

    if (tid < 64) {
        lcnt[tid] = 0;
        int n = nbase + tid;
        ssl[tid] = (n < n_nodes) ? s_src[n] : 0.f;
    }
    __syncthreads();

    const int ecnt = min(gcur[sub], CAPH);
    for (int i = tid; i < ecnt; i += 512) {
        unsigned v = pk[(size_t)sub * CAPH + i];
        int s63 = (int)(v >> 16);
        int d = (int)(v & 0xffffu);
        float w = edge_w(ssl[s63] + s_dst[d]);
        int r = atomicAdd(&lcnt[s63], 1);
        if (r < CAP) {
            uint2 e; e.x = (unsigned)d; e.y = __float_as_uint(w);
            edl[s63 * CAP + ((r + 2 * (s63 & 7)) & (CAP - 1))] = e;
        }
    }
    __syncthreads();

    // residue-class rank sort: thread tid owns node nl0 = tid (class tid&7,
    // member tid>>3); rank within its 8-node class (desc degree, idx tiebreak)
    if (tid < 64) {
        const int cls = tid & 7, mem = tid >> 3;
        const int my = lcnt[tid];
        int r = 0;
        #pragma unroll
        for (int j = 0; j < 8; ++j) {
            int dj = lcnt[j * 8 + cls];
            r += (dj > my) || (dj == my && j < mem);
        }
        nsort[r * 8 + cls] = tid;
    }
    __syncthreads();

    const int wv = tid >> 6, lane = tid & 63;   // 8 waves
    const int g  = lane >> 3;      // group = residue class of its node
    const int fl = lane & 7;       // feature octet
    const int nl = nsort[wv * 8 + g];   // rank-wv node of class g; nl&7 == g
    const int n  = nbase + nl;
    const int rot = 2 * (nl & 7);  // bucket slot rotation (matches writer)
    const int cn = (n < n_nodes) ? min(lcnt[nl], CAP) : 0;
    const int bbase = nl * CAP;

    float ac[8] = {0.f,0.f,0.f,0.f,0.f,0.f,0.f,0.f};
    float rs = 0.f;
    int t = 0;
    for (; t + 4 <= cn; t += 4) {
        uint2 e0 = edl[bbase + ((t + 0 + rot) & (CAP - 1))];
        uint2 e1 = edl[bbase + ((t + 1 + rot) & (CAP - 1))];
        uint2 e2 = edl[bbase + ((t + 2 + rot) & (CAP - 1))];
        uint2 e3 = edl[bbase + ((t + 3 + rot) & (CAP - 1))];
        h8 x0 = *(const h8*)&data_h[(size_t)e0.x * OUT_F + 8 * fl];
        h8 x1 = *(const h8*)&data_h[(size_t)e1.x * OUT_F + 8 * fl];
        h8 x2 = *(const h8*)&data_h[(size_t)e2.x * OUT_F + 8 * fl];
        h8 x3 = *(const h8*)&data_h[(size_t)e3.x * OUT_F + 8 * fl];
        float w0 = __uint_as_float(e0.y);
        float w1 = __uint_as_float(e1.y);
        float w2 = __uint_as_float(e2.y);
        float w3 = __uint_as_float(e3.y);
        #pragma unroll
        for (int i = 0; i < 8; ++i) ac[i] = fmaf(w0, (float)x0[i], ac[i]);
        #pragma unroll
        for (int i = 0; i < 8; ++i) ac[i] = fmaf(w1, (float)x1[i], ac[i]);
        #pragma unroll
        for (int i = 0; i < 8; ++i) ac[i] = fmaf(w2, (float)x2[i], ac[i]);
        #pragma unroll
        for (int i = 0; i < 8; ++i) ac[i] = fmaf(w3, (float)x3[i], ac[i]);
        rs += (w0 + w1) + (w2 + w3);
    }
    for (; t < cn; ++t) {
        uint2 e0 = edl[bbase + ((t + rot) & (CAP - 1))];
        float w0 = __uint_as_float(e0.y);
        h8 x0 = *(const h8*)&data_h[(size_t)e0.x * OUT_F + 8 * fl];
        #pragma unroll
        for (int i = 0; i < 8; ++i) ac[i] = fmaf(w0, (float)x0[i], ac[i]);
        rs += w0;
    }

    if (n < n_nodes) {
        size_t o = (size_t)n * OUT_F + 8 * fl;
        f4 r0, r1;
        if (rs == 0.f) {
            h8 xv = *(const h8*)&data_h[o];
            r0[0] = (float)xv[0]; r0[1] = (float)xv[1];
            r0[2] = (float)xv[2]; r0[3] = (float)xv[3];
            r1[0] = (float)xv[4]; r1[1] = (float)xv[5];
            r1[2] = (float)xv[6]; r1[3] = (float)xv[7];
        } else {
            float inv = 1.f / rs;
            r0[0] = ac[0] * inv; r0[1] = ac[1] * inv;
            r0[2] = ac[2] * inv; r0[3] = ac[3] * inv;
            r1[0] = ac[4] * inv; r1[1] = ac[5] * inv;
            r1[2] = ac[6] * inv; r1[3] = ac[7] * inv;
        }
        __builtin_nontemporal_store(r0, (f4*)&out[o]);
        __builtin_nontemporal_store(r1, (f4*)&out[o + 4]);
    }
}

extern "C" void kernel_launch(void* const* d_in, const int* in_sizes, int n_in,
                              void* d_out, int out_size, void* d_ws, size_t ws_size,
                              hipStream_t stream)
{
    const float* h   = (const float*)d_in[0];
    const int*   adj = (const int*)  d_in[1];   // (2,E) int32
    const float* W   = (const float*)d_in[2];
    const float* b   = (const float*)d_in[3];
    const float* a   = (const float*)d_in[4];
    float* out = (float*)d_out;

    const int n_nodes = in_sizes[0] / IN_F;
    const int n_edges = in_sizes[1] / 2;
    const int* src = adj;
    const int* dst = adj + n_edges;
    const int nsub = (n_nodes + SUBSZ - 1) >> SUBSH;

    // ws: data_h f16[N*64] | pk u32[nsub*CAPH] | s_src f32[N] | s_dst f32[N]
    //   | gcur i32[nsub]
    char* p = (char*)d_ws;
    _Float16*       data_h = (_Float16*)p;       p += (size_t)n_nodes * OUT_F * 2;
    unsigned*       pk     = (unsigned*)p;       p += (size_t)nsub * CAPH * 4;
    float*          s_src  = (float*)p;          p += (size_t)n_nodes * 4;
    float*          s_dst  = (float*)p;          p += (size_t)n_nodes * 4;
    int*            gcur   = (int*)p;            p += (size_t)nsub * 4;

    (void)hipMemsetAsync(gcur, 0, (size_t)nsub * sizeof(int), stream);

    const int g_p1  = (n_edges + 4095) / 4096;
    const int g_lin = (n_nodes + 63) / 64;
    k_p1<<<g_p1 + g_lin, 256, 0, stream>>>(
        h, W, b, a, src, dst, gcur, pk, data_h, s_src, s_dst,
        n_nodes, n_edges, g_p1);

    k_bin<<<nsub, 512, 0, stream>>>(
        pk, gcur, s_src, s_dst, data_h, out, n_nodes);
}